// Round 10
// baseline (827.396 us; speedup 1.0000x reference)
//
#include <hip/hip_runtime.h>

// QLSTM: B=512, T=1024, IN=1, H=64.
// R10 = R0's verified 586us skeleton EXACTLY (4 waves/elem = gate/wave,
// grid 512, 2 blocks/CU, ONE barrier/step, LDS h-broadcast, dbuf act
// exchange) + ONE change: the 64 recurrent weights per lane are PARKED IN
// AGPRs at init (v_accvgpr_write_b32) and pulled per-use with volatile
// v_accvgpr_read_b32.
//
// Why: R1-R4 proved the VGPR allocator refuses residency (caps 44-88,
// spills volatile/pinned values to scratch). R7/R9 proved moving the
// per-step re-fetch between pipes (L1 vs LDS) never helps -- R9 had
// IDENTICAL issue cycles to R0 (747 vs 745 cyc/SIMD/step) and only added
// lgkmcnt serialization. The real cost is ~700 cyc/step of exposed load
// latency inside the serial FMA chain (16 loads, only ~2-3 in flight at
// VGPR=44). AGPRs are a separate allocation class: asm-opaque (no remat),
// expensive to spill (allocator avoids), and 64 AGPR + ~50 VGPR fits the
// 4-waves/SIMD unified-file bucket. Weight memory traffic per step -> 0;
// +64 full-rate accvgpr_read issues (+~128 cyc) buys -~700 cyc of stall.
//
// FMA order, h broadcast, act exchange, output: byte-identical to R0
// (absmax 0.0).

#define TLEN 1024
#define HID  64

__device__ __forceinline__ float fast_sigmoid(float x) {
    return __builtin_amdgcn_rcpf(1.0f + __expf(-x));   // hw exp + hw rcp
}
__device__ __forceinline__ float fast_tanh(float x) {
    return __builtin_fmaf(2.0f, fast_sigmoid(2.0f * x), -1.0f);
}

__global__ __launch_bounds__(256, 2)
void qlstm_kernel(const float* __restrict__ x,      // [B, T, 1]
                  const float* __restrict__ W_ih,   // [256, 1]
                  const float* __restrict__ W_hh,   // [256, 64]
                  const float* __restrict__ b_ih,   // [256]
                  const float* __restrict__ b_hh,   // [256]
                  const float* __restrict__ W_lin,  // [1, 64]
                  const float* __restrict__ b_lin,  // [1]
                  float* __restrict__ out)          // [B]
{
    const int b   = blockIdx.x;
    const int tid = threadIdx.x;
    const int w   = tid >> 6;   // wave id == gate id (i,f,g,o)
    const int l   = tid & 63;   // hidden unit

    __shared__ __align__(16) float xs[TLEN];          // 4 KB
    __shared__ __align__(16) float hs4[4][HID];       // per-wave private h
    __shared__ __align__(16) float act[2][4][HID];    // double-buffered gates

    // Stage this batch element's x row: 1024 floats, one float4 per thread.
    ((float4*)xs)[tid] = ((const float4*)(x + (size_t)b * TLEN))[tid];

    // Load this wave's gate row (64 weights) ONCE and park it in AGPRs.
    // aw[] is constrained to the AGPR class by the asm; values become
    // opaque (cannot be rematerialized from W_hh inside the loop).
    const int row = w * HID + l;
    const float4* Wr = (const float4*)(W_hh + (size_t)row * HID);
    float aw[64];
    #pragma unroll
    for (int q = 0; q < 16; ++q) {
        const float4 t = Wr[q];
        asm volatile("v_accvgpr_write_b32 %0, %1" : "=a"(aw[4*q+0]) : "v"(t.x));
        asm volatile("v_accvgpr_write_b32 %0, %1" : "=a"(aw[4*q+1]) : "v"(t.y));
        asm volatile("v_accvgpr_write_b32 %0, %1" : "=a"(aw[4*q+2]) : "v"(t.z));
        asm volatile("v_accvgpr_write_b32 %0, %1" : "=a"(aw[4*q+3]) : "v"(t.w));
    }

    const float u    = W_ih[row];                 // IN == 1
    const float bias = b_ih[row] + b_hh[row];
    const float wlin = W_lin[l];

    float c = 0.0f, h = 0.0f;
    hs4[w][l] = 0.0f;
    __syncthreads();   // xs + hs4 ready

    const float* hsw = hs4[w];

    for (int t = 0; t < TLEN; ++t) {
        const int p = t & 1;
        const float xt = xs[t];                   // same-address broadcast

        // acc = W_hh[row,:] . h + x_t*u + bias.  h from private LDS copy
        // (broadcast b128 reads); weights pulled from AGPRs (full-rate
        // VALU, no memory). FMA order identical to the verified kernel.
        float acc = __builtin_fmaf(xt, u, bias);
        #pragma unroll
        for (int q = 0; q < 16; ++q) {
            const float4 hk = *(const float4*)&hsw[4 * q];  // ds_read_b128 bcast
            float w0, w1, w2, w3;
            asm volatile("v_accvgpr_read_b32 %0, %1" : "=v"(w0) : "a"(aw[4*q+0]));
            asm volatile("v_accvgpr_read_b32 %0, %1" : "=v"(w1) : "a"(aw[4*q+1]));
            asm volatile("v_accvgpr_read_b32 %0, %1" : "=v"(w2) : "a"(aw[4*q+2]));
            asm volatile("v_accvgpr_read_b32 %0, %1" : "=v"(w3) : "a"(aw[4*q+3]));
            acc = __builtin_fmaf(hk.x, w0, acc);
            acc = __builtin_fmaf(hk.y, w1, acc);
            acc = __builtin_fmaf(hk.z, w2, acc);
            acc = __builtin_fmaf(hk.w, w3, acc);
        }

        // This wave's activation (wave-uniform branch).
        const float a = (w == 2) ? fast_tanh(acc) : fast_sigmoid(acc);
        act[p][w][l] = a;                         // stride-1, conflict-free
        __syncthreads();                          // the ONE barrier per step

        // Redundant elementwise update in every wave.
        const float ai = act[p][0][l];
        const float af = act[p][1][l];
        const float ag = act[p][2][l];
        const float ao = act[p][3][l];
        c = __builtin_fmaf(af, c, ai * ag);
        h = ao * fast_tanh(c);
        hs4[w][l] = h;                            // private copy; no barrier
    }

    // out[b] = dot(h, W_lin) + b_lin  (wave 0 only)
    if (w == 0) {
        float v = h * wlin;
        #pragma unroll
        for (int off = 32; off > 0; off >>= 1)
            v += __shfl_down(v, off, 64);
        if (l == 0) out[b] = v + b_lin[0];
    }
}

extern "C" void kernel_launch(void* const* d_in, const int* in_sizes, int n_in,
                              void* d_out, int out_size, void* d_ws, size_t ws_size,
                              hipStream_t stream) {
    const float* x     = (const float*)d_in[0];
    const float* W_ih  = (const float*)d_in[1];
    const float* W_hh  = (const float*)d_in[2];
    const float* b_ih  = (const float*)d_in[3];
    const float* b_hh  = (const float*)d_in[4];
    const float* W_lin = (const float*)d_in[5];
    const float* b_lin = (const float*)d_in[6];
    float* out = (float*)d_out;

    const int B = out_size;  // 512
    qlstm_kernel<<<B, 256, 0, stream>>>(x, W_ih, W_hh, b_ih, b_hh, W_lin, b_lin, out);
}